// Round 1
// baseline (232.587 us; speedup 1.0000x reference)
//
#include <hip/hip_runtime.h>
#include <hip/hip_bf16.h>
#include <cstdint>

#define ALPHA 8.3f

typedef __attribute__((ext_vector_type(8))) short bf16x8;
typedef __attribute__((ext_vector_type(4))) float f32x4;

// bf16 weights, layout [tap][o][c]  (9*128*128)
__device__ __align__(16) short g_wt[9 * 128 * 128];

__device__ __forceinline__ short f2bf(float f) {
    union { float f; uint32_t u; } v; v.f = f;
    uint32_t r = v.u + 0x7fffu + ((v.u >> 16) & 1u);
    return (short)(r >> 16);
}

// weight: (Cout=128, Cin=128, 3, 3) fp32  ->  g_wt[tap][o][c] bf16
__global__ __launch_bounds__(256) void wt_transform(const float* __restrict__ w) {
    int tid = blockIdx.x * 256 + threadIdx.x;   // == tap*16384 + o*128 + c
    int c = tid & 127;
    int o = (tid >> 7) & 127;
    int tap = tid >> 14;
    g_wt[tid] = f2bf(w[(o * 128 + c) * 9 + tap]);
}

// One block per (b,h): computes out[b, 0..127, h, 0..127].
// GEMM per tap: D[o][w] += Wt[o][c] * (x[c][h+dh][w+dw] * sim[w][tap])
__global__ __launch_bounds__(256) void depthconv_main(
    const float* __restrict__ x, const float* __restrict__ depth,
    const float* __restrict__ bias, float* __restrict__ out)
{
    __shared__ __align__(16) short Atile[128 * 128]; // bf16, swizzled [w][c]
    __shared__ float simL[9][128];
    __shared__ float dcL[128];

    const int blk = blockIdx.x;
    const int b = blk >> 7;
    const int h = blk & 127;
    const int tid = threadIdx.x;
    const int lane = tid & 63;
    const int wid = tid >> 6;
    const int wm = wid >> 1;   // o-half of the wave
    const int wn = wid & 1;    // w-half of the wave

    const float* xb = x + (size_t)b * (128 * 128 * 128);
    const float* db = depth + (size_t)b * (128 * 128);

    if (tid < 128) dcL[tid] = db[h * 128 + tid];
    __syncthreads();

    {   // sim[tap][w] = exp(-ALPHA*|d(h,w) - d(h+dh,w+dw)|), padded depth = 0
        int w = tid & 127;
        for (int tap = (tid >> 7); tap < 9; tap += 2) {
            int dh = tap / 3 - 1, dw = tap % 3 - 1;
            int hh = h + dh, ww = w + dw;
            float dsv = 0.f;
            if (hh >= 0 && hh < 128 && ww >= 0 && ww < 128) dsv = db[hh * 128 + ww];
            simL[tap][w] = __expf(-ALPHA * fabsf(dcL[w] - dsv));
        }
    }

    f32x4 acc[4][4];
    #pragma unroll
    for (int i = 0; i < 4; ++i)
        #pragma unroll
        for (int j = 0; j < 4; ++j)
            acc[i][j] = (f32x4){0.f, 0.f, 0.f, 0.f};

    const int wA = tid & 127;   // the w-row this thread stages
    const int chalf = tid >> 7; // which 64-channel half
    char* atp = (char*)Atile;

    for (int tap = 0; tap < 9; ++tap) {
        const int dh = tap / 3 - 1, dw = tap % 3 - 1;
        const int hh = h + dh;
        if (hh < 0 || hh >= 128) continue;   // uniform per block
        __syncthreads();   // protect Atile from previous tap's readers

        // ---- build A tile: Atile[w][c] = bf16( x[c][hh][w+dw] * sim[tap][w] )
        {
            int ww = wA + dw;
            bool valid = (ww >= 0) && (ww < 128);
            int wwc = valid ? ww : 0;
            float simv = valid ? simL[tap][wA] : 0.f;
            const float* xcol = xb + (hh * 128 + wwc);
            const int swz = (wA & 7) << 4;
            #pragma unroll
            for (int oct = 0; oct < 8; ++oct) {
                int c0 = (chalf * 8 + oct) * 8;
                const float* p = xcol + (size_t)c0 * 16384;
                bf16x8 pk;
                #pragma unroll
                for (int i = 0; i < 8; ++i) {
                    float vv = p[(size_t)i * 16384] * simv;
                    pk[i] = f2bf(vv);
                }
                int byte = ((wA << 8) | (c0 << 1)) ^ swz;
                *reinterpret_cast<bf16x8*>(atp + byte) = pk;
            }
        }
        __syncthreads();

        // ---- MFMA: acc[o][w] += Wt[o][c] * Atile[w][c]
        const short* wtap = g_wt + tap * 16384;
        #pragma unroll
        for (int ks = 0; ks < 4; ++ks) {
            const int cb = ks * 32 + ((lane >> 4) << 3);
            bf16x8 bfr[4], afr[4];
            #pragma unroll
            for (int j = 0; j < 4; ++j) {
                int wrow = wn * 64 + j * 16 + (lane & 15);
                int byte = ((wrow << 8) | (cb << 1)) ^ ((wrow & 7) << 4);
                bfr[j] = *reinterpret_cast<const bf16x8*>(atp + byte);
            }
            #pragma unroll
            for (int i = 0; i < 4; ++i) {
                int orow = wm * 64 + i * 16 + (lane & 15);
                afr[i] = *reinterpret_cast<const bf16x8*>(wtap + orow * 128 + cb);
            }
            #pragma unroll
            for (int i = 0; i < 4; ++i)
                #pragma unroll
                for (int j = 0; j < 4; ++j)
                    acc[i][j] = __builtin_amdgcn_mfma_f32_16x16x32_bf16(
                        afr[i], bfr[j], acc[i][j], 0, 0, 0);
        }
    }

    // ---- epilogue: out[b][o][h][w] = acc + bias[o]
    #pragma unroll
    for (int i = 0; i < 4; ++i) {
        const int ob = wm * 64 + i * 16 + ((lane >> 4) << 2);
        #pragma unroll
        for (int r = 0; r < 4; ++r) {
            const int o = ob + r;
            const float bv = bias[o];
            float* orow = out + (((size_t)(b * 128 + o)) * 128 + h) * 128;
            #pragma unroll
            for (int j = 0; j < 4; ++j) {
                int w0 = wn * 64 + j * 16 + (lane & 15);
                orow[w0] = acc[i][j][r] + bv;
            }
        }
    }
}

extern "C" void kernel_launch(void* const* d_in, const int* in_sizes, int n_in,
                              void* d_out, int out_size, void* d_ws, size_t ws_size,
                              hipStream_t stream) {
    const float* x     = (const float*)d_in[0];
    const float* depth = (const float*)d_in[1];
    const float* wgt   = (const float*)d_in[2];
    const float* bias  = (const float*)d_in[3];
    float* out = (float*)d_out;

    hipLaunchKernelGGL(wt_transform, dim3(576), dim3(256), 0, stream, wgt);
    hipLaunchKernelGGL(depthconv_main, dim3(8 * 128), dim3(256), 0, stream,
                       x, depth, bias, out);
}

// Round 2
// 218.027 us; speedup vs baseline: 1.0668x; 1.0668x over previous
//
#include <hip/hip_runtime.h>
#include <hip/hip_bf16.h>
#include <cstdint>

#define ALPHA 8.3f

typedef __attribute__((ext_vector_type(8))) short bf16x8;
typedef __attribute__((ext_vector_type(4))) float f32x4;

// bf16 weights, layout [tap][o][c]  (9*128*128)
__device__ __align__(16) short g_wt[9 * 128 * 128];

__device__ __forceinline__ short f2bf(float f) {
    union { float f; uint32_t u; } v; v.f = f;
    uint32_t r = v.u + 0x7fffu + ((v.u >> 16) & 1u);
    return (short)(r >> 16);
}

// weight: (Cout=128, Cin=128, 3, 3) fp32  ->  g_wt[tap][o][c] bf16
__global__ __launch_bounds__(256) void wt_transform(const float* __restrict__ w) {
    int tid = blockIdx.x * 256 + threadIdx.x;   // == tap*16384 + o*128 + c
    int c = tid & 127;
    int o = (tid >> 7) & 127;
    int tap = tid >> 14;
    g_wt[tid] = f2bf(w[(o * 128 + c) * 9 + tap]);
}

// One block per (b, h, w-half): computes out[b, 0:128, h, w0:w0+64].
// Key identity: out[o][w] = sum_t sim_t[w] * P_t[o][w],
//               P_t[o][w] = sum_c W_t[o][c] * x[c][h+kh-1][w+kw-1]
// sim factors out of the channel sum, so input rows are staged UNSCALED once,
// and each tap is pure {LDS read + MFMA} + a per-element VALU fma.
__global__ __launch_bounds__(256, 3) void depthconv_main(
    const float* __restrict__ x, const float* __restrict__ depth,
    const float* __restrict__ bias, float* __restrict__ out)
{
    // Xs logical layout: [row = r*66 + wl][c]  bf16, 256 B per row,
    // byte addr = ((row<<8) | (c<<1)) ^ ((row&15)<<4)   (bank-conflict-free b128)
    __shared__ __align__(16) short Xs[3 * 66 * 128];
    __shared__ float simL[9][64];

    const int blk = blockIdx.x;
    const int b = blk >> 8;
    const int rem = blk & 255;
    const int h = rem >> 1;
    const int w0 = (rem & 1) << 6;

    const int tid = threadIdx.x;
    const int lane = tid & 63;
    const int wid = tid >> 6;

    const float* xb = x + (size_t)b * (128 * 128 * 128);
    const float* db = depth + (size_t)b * (128 * 128);
    char* xsp = (char*)Xs;

    // ---- stage 3 input rows (h-1, h, h+1), columns w0-1 .. w0+64, as bf16
    // items: 3 rows x 16 c-octets x 66 columns = 3168
    for (int it = tid; it < 3168; it += 256) {
        int r = it / 1056;
        int rem2 = it - r * 1056;
        int oct = rem2 / 66;
        int wl = rem2 - oct * 66;      // 0..65
        int hh = h - 1 + r;
        int wg = w0 - 1 + wl;
        int row = r * 66 + wl;
        bf16x8 pk = (bf16x8){0, 0, 0, 0, 0, 0, 0, 0};
        if (hh >= 0 && hh < 128 && wg >= 0 && wg < 128) {
            const float* p = xb + (size_t)oct * 131072 + (size_t)hh * 128 + wg;
            #pragma unroll
            for (int i = 0; i < 8; ++i)
                pk[i] = f2bf(p[(size_t)i * 16384]);
        }
        int byte = ((row << 8) | (oct << 4)) ^ ((row & 15) << 4);
        *reinterpret_cast<bf16x8*>(xsp + byte) = pk;
    }

    // ---- sim[tap][wo] = exp(-ALPHA*|d(h,w) - d(h+kh-1,w+kw-1)|)
    for (int idx = tid; idx < 576; idx += 256) {
        int t = idx >> 6;
        int wo = idx & 63;
        int kh = t / 3, kw = t - 3 * kh;
        int w = w0 + wo;
        float dc = db[h * 128 + w];
        int hh = h + kh - 1, wg = w + kw - 1;
        float dsv = (hh >= 0 && hh < 128 && wg >= 0 && wg < 128)
                        ? db[hh * 128 + wg] : 0.f;
        simL[t][wo] = __expf(-ALPHA * fabsf(dc - dsv));
    }
    __syncthreads();

    // ---- 9 taps: P = W_t * Xrow  (MFMA), then acc += sim_t * P
    // wave 'wid' owns o in [wid*32, wid*32+32), all 64 w.
    f32x4 acc[2][4];
    #pragma unroll
    for (int i = 0; i < 2; ++i)
        #pragma unroll
        for (int j = 0; j < 4; ++j)
            acc[i][j] = (f32x4){0.f, 0.f, 0.f, 0.f};

    const int obase = wid << 5;
    const int l15 = lane & 15;
    const int khi = lane >> 4;

    for (int tap = 0; tap < 9; ++tap) {
        const int r = tap / 3;
        const int kw = tap - 3 * r;
        const short* wtap = g_wt + tap * 16384;

        f32x4 P[2][4];
        #pragma unroll
        for (int i = 0; i < 2; ++i)
            #pragma unroll
            for (int j = 0; j < 4; ++j)
                P[i][j] = (f32x4){0.f, 0.f, 0.f, 0.f};

        #pragma unroll
        for (int ks = 0; ks < 4; ++ks) {
            const int cb = ks * 32 + (khi << 3);
            bf16x8 afr[2], bfr[4];
            #pragma unroll
            for (int i = 0; i < 2; ++i) {
                int orow = obase + i * 16 + l15;
                afr[i] = *reinterpret_cast<const bf16x8*>(wtap + orow * 128 + cb);
            }
            #pragma unroll
            for (int j = 0; j < 4; ++j) {
                int wl = j * 16 + l15 + kw;       // shifted read: dw folded here
                int row = r * 66 + wl;
                int byte = ((row << 8) | (cb << 1)) ^ ((row & 15) << 4);
                bfr[j] = *reinterpret_cast<const bf16x8*>(xsp + byte);
            }
            #pragma unroll
            for (int i = 0; i < 2; ++i)
                #pragma unroll
                for (int j = 0; j < 4; ++j)
                    P[i][j] = __builtin_amdgcn_mfma_f32_16x16x32_bf16(
                        afr[i], bfr[j], P[i][j], 0, 0, 0);
        }

        #pragma unroll
        for (int j = 0; j < 4; ++j) {
            float sv = simL[tap][j * 16 + l15];
            #pragma unroll
            for (int i = 0; i < 2; ++i)
                #pragma unroll
                for (int rr = 0; rr < 4; ++rr)
                    acc[i][j][rr] += sv * P[i][j][rr];
        }
    }

    // ---- epilogue: out[b][o][h][w0+wo] = acc + bias[o]
    #pragma unroll
    for (int i = 0; i < 2; ++i) {
        #pragma unroll
        for (int rr = 0; rr < 4; ++rr) {
            const int o = obase + i * 16 + (khi << 2) + rr;
            const float bv = bias[o];
            float* orow = out + (((size_t)(b * 128 + o)) * 128 + h) * 128 + w0;
            #pragma unroll
            for (int j = 0; j < 4; ++j)
                orow[j * 16 + l15] = acc[i][j][rr] + bv;
        }
    }
}

extern "C" void kernel_launch(void* const* d_in, const int* in_sizes, int n_in,
                              void* d_out, int out_size, void* d_ws, size_t ws_size,
                              hipStream_t stream) {
    const float* x     = (const float*)d_in[0];
    const float* depth = (const float*)d_in[1];
    const float* wgt   = (const float*)d_in[2];
    const float* bias  = (const float*)d_in[3];
    float* out = (float*)d_out;

    hipLaunchKernelGGL(wt_transform, dim3(576), dim3(256), 0, stream, wgt);
    hipLaunchKernelGGL(depthconv_main, dim3(8 * 128 * 2), dim3(256), 0, stream,
                       x, depth, bias, out);
}